// Round 2
// baseline (468.406 us; speedup 1.0000x reference)
//
#include <hip/hip_runtime.h>
#include <cstdint>

#define NEXP 8
#define TOPK 2
#define NTOK 4096
#define NSLOT (NTOK * TOPK)   // 8192
#define CAP 1280              // expert capacity
#define DM 2048               // d_model == hidden
#define EC (NEXP * CAP)       // 10240 binned rows
#define KT 32                 // K tiles: 2048 / 64

typedef __bf16 bf16x8 __attribute__((ext_vector_type(8)));
typedef __bf16 bf16x4 __attribute__((ext_vector_type(4)));
typedef float  f32x4  __attribute__((ext_vector_type(4)));

typedef const void __attribute__((address_space(1))) gvoid;
typedef void __attribute__((address_space(3))) lvoid;

__device__ __forceinline__ void gld16(const void* g, void* l) {
  __builtin_amdgcn_global_load_lds((gvoid*)(uintptr_t)g, (lvoid*)(uintptr_t)l,
                                   16, 0, 0);
}

// ---------------------------------------------------------------- routing
__global__ void route_k(const int* __restrict__ eidx, int* __restrict__ row_token,
                        int* __restrict__ slot_dest, int* __restrict__ mcount,
                        float* __restrict__ out) {
  __shared__ int lh[256][NEXP];
  int tid = threadIdx.x;
  for (int i = tid; i < EC; i += 256) row_token[i] = -1;
#pragma unroll
  for (int e = 0; e < NEXP; ++e) lh[tid][e] = 0;
  __syncthreads();
  int base = tid * 32;
  for (int j = 0; j < 32; ++j) lh[tid][eidx[base + j]]++;
  __syncthreads();
  if (tid < NEXP) {
    int run = 0;
    for (int i = 0; i < 256; ++i) { int t = lh[i][tid]; lh[i][tid] = run; run += t; }
    mcount[tid] = run < CAP ? run : CAP;
    out[(size_t)NTOK * DM + tid] = (float)run;
  }
  __syncthreads();
  for (int j = 0; j < 32; ++j) {
    int t = base + j;
    int e = eidx[t];
    int r = lh[tid][e]++;
    if (r < CAP) { int dst = e * CAP + r; slot_dest[t] = dst; row_token[dst] = t >> 1; }
    else slot_dest[t] = -1;
  }
}

// ------------------------------------------------------- gather + fp32->bf16
__global__ void gather_k(const float* __restrict__ x, const int* __restrict__ row_token,
                         __bf16* __restrict__ xg) {
  int r = blockIdx.x;
  int c = threadIdx.x * 8;
  int tok = row_token[r];
  bf16x8 o;
  if (tok >= 0) {
    const float* src = x + (size_t)tok * DM + c;
    float4 a = *(const float4*)src;
    float4 b = *(const float4*)(src + 4);
    o[0] = (__bf16)a.x; o[1] = (__bf16)a.y; o[2] = (__bf16)a.z; o[3] = (__bf16)a.w;
    o[4] = (__bf16)b.x; o[5] = (__bf16)b.y; o[6] = (__bf16)b.z; o[7] = (__bf16)b.w;
  } else {
#pragma unroll
    for (int j = 0; j < 8; ++j) o[j] = (__bf16)0.f;
  }
  *(bf16x8*)(xg + (size_t)r * DM + c) = o;
}

// --------------------------------------- fp32 [E][K][N] -> bf16 [E][N][K]
__global__ void transT_k(const float* __restrict__ w, __bf16* __restrict__ wT) {
  __shared__ __bf16 t[64][65];
  int e = blockIdx.z;
  int n0 = blockIdx.x * 64, k0 = blockIdx.y * 64;
  const float* src = w + ((size_t)e << 22) + (size_t)k0 * DM + n0;
  __bf16* dst = wT + ((size_t)e << 22) + (size_t)n0 * DM + k0;
  int c = threadIdx.x & 63, r4 = threadIdx.x >> 6;
#pragma unroll
  for (int p = 0; p < 16; ++p) {
    int r = p * 4 + r4;
    t[r][c] = (__bf16)src[(size_t)r * DM + c];
  }
  __syncthreads();
  int j = threadIdx.x & 15, rr0 = threadIdx.x >> 4;
#pragma unroll
  for (int q = 0; q < 4; ++q) {
    int rr = q * 16 + rr0;
    bf16x4 v;
    v[0] = t[4 * j + 0][rr];
    v[1] = t[4 * j + 1][rr];
    v[2] = t[4 * j + 2][rr];
    v[3] = t[4 * j + 3][rr];
    *(bf16x4*)(dst + (size_t)rr * DM + 4 * j) = v;  // 8B coalesced stores
  }
}

// ------------------------------------------------------------------- GEMM
// C[rows,N] = A[rows,K] * BT[N,K]^T per expert. BM=128, BN=256, BK=64.
// 512 threads = 8 waves (2 M x 4 N), per-wave 64x64 out, acc[4][4].
// Pipeline: 3-buffer LDS rotation, prefetch distance 2 tiles.
//   top of tile t: s_waitcnt vmcnt(6)  (tile t landed; t+1's 6 sweeps in
//   flight) -> s_barrier -> phases issue tile t+2 into buf (t+2)%3, which
//   held tile t-1 (all reads of t-1 delivered before this barrier: each
//   wave's last ds_read of t-1 was consumed by an MFMA behind lgkmcnt).
// LDS rows XOR-swizzled (chunk ^= row&7), staged via inverse-swizzled
// global source + linear LDS dest (rule #21); measured 0 bank conflicts.
template<bool SWI>
__global__ __launch_bounds__(512, 2)
void gemm3_k(const __bf16* __restrict__ A0, const __bf16* __restrict__ BT,
             __bf16* C, __bf16* U, const int* __restrict__ mcount) {
  int e = blockIdx.z, mt = blockIdx.y, nt = blockIdx.x;
  int mc = mcount[e];
  if (mt * 128 >= mc) return;

  __shared__ __align__(16) char smem[48 * 1024 + 96 * 1024];
  char* lA = smem;                 // 3 x 16KB  (128 rows x 128B)
  char* lB = smem + 48 * 1024;     // 3 x 32KB  (256 rows x 128B)

  int tid = threadIdx.x, w = tid >> 6, l = tid & 63;
  int wr = w >> 2, wc = w & 3;
  int lr = l & 15, kg = l >> 4;

  const char* gA = (const char*)(A0 + (size_t)(e * CAP + mt * 128) * DM);
  const char* gB = (const char*)(BT + ((size_t)e * DM + (size_t)nt * 256) * DM);

  // one sweep = 512 threads x 16B = 8KB. A tile: 2 sweeps; B tile: 4 sweeps.
  auto stageA = [&](int t, int buf, int s) {
    int idx = s * 512 + tid; int r = idx >> 3; int cl = (idx & 7) ^ (r & 7);
    gld16(gA + (size_t)r * 4096 + (size_t)t * 128 + cl * 16,
          lA + buf * 16384 + s * 8192 + w * 1024);
  };
  auto stageB = [&](int t, int buf, int s) {
    int idx = s * 512 + tid; int r = idx >> 3; int cl = (idx & 7) ^ (r & 7);
    gld16(gB + (size_t)r * 4096 + (size_t)t * 128 + cl * 16,
          lB + buf * 32768 + s * 8192 + w * 1024);
  };

  // prologue: tiles 0 -> buf0, 1 -> buf1 (12 sweeps in flight)
  stageA(0, 0, 0); stageA(0, 0, 1);
  stageB(0, 0, 0); stageB(0, 0, 1); stageB(0, 0, 2); stageB(0, 0, 3);
  stageA(1, 1, 0); stageA(1, 1, 1);
  stageB(1, 1, 0); stageB(1, 1, 1); stageB(1, 1, 2); stageB(1, 1, 3);

  f32x4 acc[4][4];
#pragma unroll
  for (int m = 0; m < 4; ++m)
#pragma unroll
    for (int n = 0; n < 4; ++n)
#pragma unroll
      for (int j = 0; j < 4; ++j) acc[m][n][j] = 0.f;

  int cb = 0, sb = 2;
#pragma unroll 1
  for (int t = 0; t < KT; ++t) {
    if (t < KT - 1) asm volatile("s_waitcnt vmcnt(6)" ::: "memory");
    else            asm volatile("s_waitcnt vmcnt(0)" ::: "memory");
    __builtin_amdgcn_s_barrier();
    __builtin_amdgcn_sched_barrier(0);
    bool st = (t < KT - 2);

    // ---- phase 0 (k-slab 0: chunks kg)
    if (st) { stageA(t + 2, sb, 0); stageA(t + 2, sb, 1); stageB(t + 2, sb, 0); }
    {
      bf16x8 af[4], bf[4];
#pragma unroll
      for (int m = 0; m < 4; ++m) {
        int r = wr * 64 + m * 16 + lr;
        af[m] = *(const bf16x8*)(lA + cb * 16384 + r * 128 + ((kg ^ (r & 7)) * 16));
      }
#pragma unroll
      for (int n = 0; n < 4; ++n) {
        int r = wc * 64 + n * 16 + lr;
        bf[n] = *(const bf16x8*)(lB + cb * 32768 + r * 128 + ((kg ^ (r & 7)) * 16));
      }
      __builtin_amdgcn_s_setprio(1);
#pragma unroll
      for (int m = 0; m < 4; ++m)
#pragma unroll
        for (int n = 0; n < 4; ++n)
          acc[m][n] = __builtin_amdgcn_mfma_f32_16x16x32_bf16(af[m], bf[n],
                                                              acc[m][n], 0, 0, 0);
      __builtin_amdgcn_s_setprio(0);
    }

    // ---- phase 1 (k-slab 1: chunks 4+kg)
    if (st) { stageB(t + 2, sb, 1); stageB(t + 2, sb, 2); stageB(t + 2, sb, 3); }
    {
      int ck = 4 + kg;
      bf16x8 af[4], bf[4];
#pragma unroll
      for (int m = 0; m < 4; ++m) {
        int r = wr * 64 + m * 16 + lr;
        af[m] = *(const bf16x8*)(lA + cb * 16384 + r * 128 + ((ck ^ (r & 7)) * 16));
      }
#pragma unroll
      for (int n = 0; n < 4; ++n) {
        int r = wc * 64 + n * 16 + lr;
        bf[n] = *(const bf16x8*)(lB + cb * 32768 + r * 128 + ((ck ^ (r & 7)) * 16));
      }
      __builtin_amdgcn_s_setprio(1);
#pragma unroll
      for (int m = 0; m < 4; ++m)
#pragma unroll
        for (int n = 0; n < 4; ++n)
          acc[m][n] = __builtin_amdgcn_mfma_f32_16x16x32_bf16(af[m], bf[n],
                                                              acc[m][n], 0, 0, 0);
      __builtin_amdgcn_s_setprio(0);
    }
    cb = cb == 2 ? 0 : cb + 1;
    sb = sb == 2 ? 0 : sb + 1;
  }

  // ---- epilogue: C/D layout col=lane&15, row=(lane>>4)*4+j [m89-verified]
  int rg = l >> 4;
#pragma unroll
  for (int m = 0; m < 4; ++m)
#pragma unroll
    for (int n = 0; n < 4; ++n)
#pragma unroll
      for (int j = 0; j < 4; ++j) {
        int row = e * CAP + mt * 128 + wr * 64 + m * 16 + rg * 4 + j;
        int col = nt * 256 + wc * 64 + n * 16 + lr;
        size_t off = (size_t)row * DM + col;
        float v = acc[m][n][j];
        if constexpr (SWI) {
          float u = (float)U[off];
          float s = u / (1.f + __expf(-u));
          C[off] = (__bf16)(s * v);            // h = silu(u) * v, in place
        } else {
          C[off] = (__bf16)v;
        }
      }
}

// --------------------------------------------- combine: y[tok] = sum w * ye
__global__ void combine_k(const __bf16* __restrict__ ye, const int* __restrict__ slot_dest,
                          const float* __restrict__ ew, float* __restrict__ out) {
  int tok = blockIdx.x;
  int c = threadIdx.x * 8;
  int d0 = slot_dest[2 * tok], d1 = slot_dest[2 * tok + 1];
  float w0 = ew[2 * tok], w1 = ew[2 * tok + 1];
  float r[8];
#pragma unroll
  for (int j = 0; j < 8; ++j) r[j] = 0.f;
  if (d0 >= 0) {
    bf16x8 y0 = *(const bf16x8*)(ye + (size_t)d0 * DM + c);
#pragma unroll
    for (int j = 0; j < 8; ++j) r[j] += w0 * (float)y0[j];
  }
  if (d1 >= 0) {
    bf16x8 y1 = *(const bf16x8*)(ye + (size_t)d1 * DM + c);
#pragma unroll
    for (int j = 0; j < 8; ++j) r[j] += w1 * (float)y1[j];
  }
  float* dst = out + (size_t)tok * DM + c;
  float4 o0; o0.x = r[0]; o0.y = r[1]; o0.z = r[2]; o0.w = r[3];
  float4 o1; o1.x = r[4]; o1.y = r[5]; o1.z = r[6]; o1.w = r[7];
  *(float4*)dst = o0;
  *(float4*)(dst + 4) = o1;
}

extern "C" void kernel_launch(void* const* d_in, const int* in_sizes, int n_in,
                              void* d_out, int out_size, void* d_ws, size_t ws_size,
                              hipStream_t stream) {
  const float* x  = (const float*)d_in[0];
  const float* ew = (const float*)d_in[1];
  const int*   ei = (const int*)d_in[2];
  const float* w1 = (const float*)d_in[3];
  const float* w2 = (const float*)d_in[4];
  const float* w3 = (const float*)d_in[5];
  float* out = (float*)d_out;
  char* ws = (char*)d_ws;

  // ws layout (~144 MB): xg (later ye) | uB (u -> h in place) | wT | ints
  const size_t SZ_MAT = (size_t)EC * DM * 2;            // 41,943,040 B
  __bf16* xg = (__bf16*)ws;                             // xg, then ye
  __bf16* uB = (__bf16*)(ws + SZ_MAT);                  // u, then h
  __bf16* wT = (__bf16*)(ws + 2 * SZ_MAT);              // [8][2048][2048] bf16
  char* ints = ws + 2 * SZ_MAT + (size_t)NEXP * DM * DM * 2;
  int* row_token = (int*)ints;
  int* slot_dest = row_token + EC;
  int* mcount    = slot_dest + NSLOT;

  dim3 tgrid(32, 32, NEXP);
  dim3 ggrid(8, 10, NEXP);                              // nt(256-wide), mt, e

  route_k<<<1, 256, 0, stream>>>(ei, row_token, slot_dest, mcount, out);
  gather_k<<<EC, 256, 0, stream>>>(x, row_token, xg);

  transT_k<<<tgrid, 256, 0, stream>>>(w1, wT);
  gemm3_k<false><<<ggrid, 512, 0, stream>>>(xg, wT, uB, nullptr, mcount); // u

  transT_k<<<tgrid, 256, 0, stream>>>(w3, wT);
  gemm3_k<true><<<ggrid, 512, 0, stream>>>(xg, wT, uB, uB, mcount);       // h

  transT_k<<<tgrid, 256, 0, stream>>>(w2, wT);
  gemm3_k<false><<<ggrid, 512, 0, stream>>>(uB, wT, xg, nullptr, mcount); // ye

  combine_k<<<NTOK, 256, 0, stream>>>(xg, slot_dest, ew, out);
}